// Round 6
// baseline (253.928 us; speedup 1.0000x reference)
//
#include <hip/hip_runtime.h>

typedef __attribute__((ext_vector_type(8))) short bf16x8;
typedef __attribute__((ext_vector_type(8))) _Float16 f16x8;
typedef __attribute__((ext_vector_type(2))) __fp16 fp16v2;
typedef __attribute__((ext_vector_type(16))) float f32x16;

#define DDIM 128
#define NADDR 4096
#define VDIM 512
#define NT 32
#define ITERS (NADDR/NT)
#define LOG2E 1.44269504088896340736f

// pack bf16-trunc(lo) into low short, bf16-trunc(hi) into high short
__device__ __forceinline__ unsigned pkhi(float hi, float lo){
  return __builtin_amdgcn_perm(__float_as_uint(hi), __float_as_uint(lo), 0x07060302u);
}

// ---------- pre-pass 1: addr f32 [4096][128] -> Ktile f16, tiled ----------
// Per n-tile nt (32 n x 128 d): f16x8 element (t, c) holds
// addr[nt*32 + (t>>4) + 16c][(t&15)*8 .. +8), so the main kernel's staging
// load kbase[nt*512 + t*2 + c] is fully coalesced and needs zero VALU.
__global__ __launch_bounds__(256)
void prep_k(const float* __restrict__ addr, _Float16* __restrict__ kt)
{
  const int nt = blockIdx.x, t = threadIdx.x;
  const float* src = addr + (size_t)nt * NT * DDIM;
  f16x8* dst = (f16x8*)kt + (size_t)nt * 512;
  const int r = t >> 4, c8 = (t & 15) * 8;
  #pragma unroll
  for (int c = 0; c < 2; ++c){
    const float* s = src + (size_t)(r + 16*c) * DDIM + c8;
    float4 a = *(const float4*)s;
    float4 b = *(const float4*)(s + 4);
    union { f16x8 v; fp16v2 h[4]; } u;
    u.h[0] = __builtin_amdgcn_cvt_pkrtz(a.x, a.y);
    u.h[1] = __builtin_amdgcn_cvt_pkrtz(a.z, a.w);
    u.h[2] = __builtin_amdgcn_cvt_pkrtz(b.x, b.y);
    u.h[3] = __builtin_amdgcn_cvt_pkrtz(b.z, b.w);
    dst[t*2 + c] = u.v;
  }
}

// ---------- pre-pass 2: bank f32 [4096][512] -> Vtile bf16, transposed+tiled
// Per (nt, vblk) tile: uint4 pair (t, i) holds bf16 of
// bank[nt*32 + (t>>7)*16 + e][vblk*128 + (t&127)] for e = i*8.. (pkhi pairs),
// i.e. exactly the old in-loop transpose staging, done ONCE instead of 32x.
__global__ __launch_bounds__(256)
void prep_v(const float* __restrict__ bank, short* __restrict__ vt)
{
  const int bid = blockIdx.x;            // bid = nt*4 + vblk
  const int nt = bid >> 2, vblk = bid & 3;
  const int t = threadIdx.x;
  const int vv = t & 127, vnb = (t >> 7) * 16;
  const float* src = bank + (size_t)(nt*NT + vnb) * VDIM + vblk*128 + vv;
  float v[16];
  #pragma unroll
  for (int k = 0; k < 16; ++k) v[k] = src[(size_t)k * VDIM];
  uint4 p0, p1;
  p0.x = pkhi(v[1],  v[0]);  p0.y = pkhi(v[3],  v[2]);
  p0.z = pkhi(v[5],  v[4]);  p0.w = pkhi(v[7],  v[6]);
  p1.x = pkhi(v[9],  v[8]);  p1.y = pkhi(v[11], v[10]);
  p1.z = pkhi(v[13], v[12]); p1.w = pkhi(v[15], v[14]);
  uint4* dst = (uint4*)vt + ((size_t)bid*256 + t)*2;
  dst[0] = p0; dst[1] = p1;
}

// ---------- main kernel: round-3 verified structure, diet staging ----------
// Block: 128 m x 128 v, 4 waves. Wave: 32 m x 32 n x 128 v per tile.
// S^T = K.Q^T (mfma_32x32x16_f16) -> lane holds P[m=lane&31][16 n] in regs;
// P packed in-register (pkhi + permlane32_swap) -> PV A-frag; denominator =
// MFMA(P, ones) ridealong. Staging is now 4 coalesced dwordx4 loads + 4
// ds_writes per thread per iter (conversion hoisted to pre-passes).
__global__ __launch_bounds__(256, 2)
void soft_addr_kernel(const float* __restrict__ sel,
                      const _Float16* __restrict__ kt,
                      const short* __restrict__ vt,
                      float* __restrict__ out)
{
  // sK: [n=32][d=128] f16, stride 136 (272B rows; measured conflict-free)
  // sVt:[v=128][n=32] bf16, stride 40 (80B rows; measured conflict-free)
  __shared__ __align__(16) _Float16 sK[2][32][136];
  __shared__ __align__(16) short  sVt[2][128][40];

  const int tid  = threadIdx.x;
  const int wave = tid >> 6;
  const int lane = tid & 63;
  const int h    = lane >> 5;      // half-wave
  const int c32  = lane & 31;

  const int bid  = blockIdx.x;
  const int vblk = bid & 3;
  const int mblk = bid >> 2;
  const int m0 = mblk * 128;
  const int v0 = vblk * 128;
  const int wm = wave * 32;        // wave's m-row base

  // ---- Q fragments as B operand (col m = c32, rows d = 16*ks+8*h+j), log2e-scaled
  f16x8 aQ[8];
  {
    const float* q = sel + (size_t)(m0 + wm + c32) * DDIM + 8*h;
    #pragma unroll
    for (int ks = 0; ks < 8; ++ks){
      float4 a = *(const float4*)(q + 16*ks);
      float4 b = *(const float4*)(q + 16*ks + 4);
      f16x8 f;
      f[0]=(_Float16)(a.x*LOG2E); f[1]=(_Float16)(a.y*LOG2E);
      f[2]=(_Float16)(a.z*LOG2E); f[3]=(_Float16)(a.w*LOG2E);
      f[4]=(_Float16)(b.x*LOG2E); f[5]=(_Float16)(b.y*LOG2E);
      f[6]=(_Float16)(b.z*LOG2E); f[7]=(_Float16)(b.w*LOG2E);
      aQ[ks] = f;
    }
  }

  // ---- persistent constants: zero C-operand, bf16 ones B-frag ----
  f32x16 zc;
  #pragma unroll
  for (int r=0;r<16;++r) zc[r] = 0.f;
  asm volatile("" : "+v"(zc));
  bf16x8 ones;
  #pragma unroll
  for (int i=0;i<8;++i) ones[i] = (short)0x3F80;   // bf16 1.0
  asm volatile("" : "+v"(ones));

  f32x16 oAcc[4];
  #pragma unroll
  for (int jv=0;jv<4;++jv)
    #pragma unroll
    for (int r=0;r<16;++r) oAcc[jv][r] = 0.f;
  f32x16 oDen;
  #pragma unroll
  for (int r=0;r<16;++r) oDen[r] = 0.f;

  // staging maps (256 threads) — must mirror prep_k / prep_v element order
  const int kr  = tid >> 4;          // K rows kr, kr+16
  const int kc  = (tid & 15) * 8;    // K col base
  const int vv  = tid & 127;         // V column
  const int vnb = (tid >> 7) * 16;   // V n base {0,16}

  const f16x8* kbase = (const f16x8*)kt;                   // 512 per tile
  const uint4* vbase = (const uint4*)vt + (size_t)vblk*512; // 2048 per n-tile

  f16x8 kfr[2];
  uint4 vfr[2];

  // prologue: load tile 0
  kfr[0] = kbase[tid*2];
  kfr[1] = kbase[tid*2 + 1];
  vfr[0] = vbase[(size_t)tid*2];
  vfr[1] = vbase[(size_t)tid*2 + 1];

  for (int t = 0; t < ITERS; ++t){
    const int b = t & 1;

    // ---- write staged tile t -> LDS buf b (pure data movement)
    *(f16x8*)&sK[b][kr]     [kc]  = kfr[0];
    *(f16x8*)&sK[b][kr + 16][kc]  = kfr[1];
    *(uint4*)&sVt[b][vv][vnb]     = vfr[0];
    *(uint4*)&sVt[b][vv][vnb + 8] = vfr[1];

    __syncthreads();   // single barrier per iteration

    // ---- prefetch tile t+1 (coalesced; drain point = next barrier)
    {
      const int n1 = (t+1) & (ITERS-1);    // wraps harmlessly on last iter
      kfr[0] = kbase[(size_t)n1*512 + tid*2];
      kfr[1] = kbase[(size_t)n1*512 + tid*2 + 1];
      vfr[0] = vbase[(size_t)n1*2048 + tid*2];
      vfr[1] = vbase[(size_t)n1*2048 + tid*2 + 1];
    }

    // ---- S^T = K . Q^T : 32n x 32m, K-dim = 128; two independent 4-chains
    __builtin_amdgcn_s_setprio(1);
    f32x16 sAcc0, sAcc1;
    {
      f16x8 aK0 = *(const f16x8*)&sK[b][c32][8*h];
      f16x8 aK1 = *(const f16x8*)&sK[b][c32][16 + 8*h];
      sAcc0 = __builtin_amdgcn_mfma_f32_32x32x16_f16(aK0, aQ[0], zc, 0,0,0);
      sAcc1 = __builtin_amdgcn_mfma_f32_32x32x16_f16(aK1, aQ[1], zc, 0,0,0);
    }
    #pragma unroll
    for (int ks=1; ks<4; ++ks){
      f16x8 aK0 = *(const f16x8*)&sK[b][c32][16*(2*ks)   + 8*h];
      f16x8 aK1 = *(const f16x8*)&sK[b][c32][16*(2*ks+1) + 8*h];
      sAcc0 = __builtin_amdgcn_mfma_f32_32x32x16_f16(aK0, aQ[2*ks],   sAcc0, 0,0,0);
      sAcc1 = __builtin_amdgcn_mfma_f32_32x32x16_f16(aK1, aQ[2*ks+1], sAcc1, 0,0,0);
    }
    __builtin_amdgcn_s_setprio(0);

    // ---- P = 2^S, bf16-trunc in-register
    unsigned dw[2][4];
    #pragma unroll
    for (int j=0;j<2;++j)
      #pragma unroll
      for (int i=0;i<4;++i){
        float pa = __builtin_amdgcn_exp2f(sAcc0[8*j + 2*i]     + sAcc1[8*j + 2*i]);
        float pb = __builtin_amdgcn_exp2f(sAcc0[8*j + 2*i + 1] + sAcc1[8*j + 2*i + 1]);
        dw[j][i] = pkhi(pb, pa);
      }

    // ---- PV + denominator ridealong: assemble A-frag via permlane32_swap
    #pragma unroll
    for (int j=0;j<2;++j){
      auto s02 = __builtin_amdgcn_permlane32_swap(dw[j][0], dw[j][2], false, false);
      auto s13 = __builtin_amdgcn_permlane32_swap(dw[j][1], dw[j][3], false, false);
      union { unsigned u[4]; bf16x8 v; } ap;
      ap.u[0] = s02[0]; ap.u[1] = s13[0]; ap.u[2] = s02[1]; ap.u[3] = s13[1];
      __builtin_amdgcn_s_setprio(1);
      oDen = __builtin_amdgcn_mfma_f32_32x32x16_bf16(ap.v, ones, oDen, 0,0,0);
      #pragma unroll
      for (int jv=0;jv<4;++jv){
        bf16x8 bV = *(const bf16x8*)&sVt[b][32*jv + c32][16*j + 8*h];
        oAcc[jv] = __builtin_amdgcn_mfma_f32_32x32x16_bf16(ap.v, bV, oAcc[jv], 0,0,0);
      }
      __builtin_amdgcn_s_setprio(0);
    }
  }

  // ---- epilogue: divide + store (D: col v = c32, row m = (r&3)+8*(r>>2)+4h)
  #pragma unroll
  for (int r=0;r<16;++r){
    const int mrow = (r&3) + 8*(r>>2) + 4*h;
    const float inv = 1.0f / oDen[r];
    float* op = out + (size_t)(m0 + wm + mrow) * VDIM + v0 + c32;
    #pragma unroll
    for (int jv=0;jv<4;++jv)
      op[32*jv] = oAcc[jv][r] * inv;
  }
}

extern "C" void kernel_launch(void* const* d_in, const int* in_sizes, int n_in,
                              void* d_out, int out_size, void* d_ws, size_t ws_size,
                              hipStream_t stream) {
  const float* sel  = (const float*)d_in[0];   // [8,2048,128]
  const float* bank = (const float*)d_in[1];   // [4096,512]
  const float* addr = (const float*)d_in[2];   // [4096,128]
  float* out = (float*)d_out;                  // [8,2048,512]

  _Float16* kt = (_Float16*)d_ws;                          // 1 MB tiled f16 K
  short*    vt = (short*)((char*)d_ws + (1u<<20));         // 4 MB tiled bf16 V^T

  hipLaunchKernelGGL(prep_k, dim3(ITERS),   dim3(256), 0, stream, addr, kt);
  hipLaunchKernelGGL(prep_v, dim3(ITERS*4), dim3(256), 0, stream, bank, vt);
  hipLaunchKernelGGL(soft_addr_kernel, dim3(512), dim3(256), 0, stream,
                     sel, kt, vt, out);
}